// Round 3
// baseline (459.018 us; speedup 1.0000x reference)
//
#include <hip/hip_runtime.h>

// CrossScan: x (B=16, C=96, H=128, W=128) fp32 -> out (B, 4, C, H*W):
//   s=0: y0[h*W+w] = x[h,w]
//   s=1: y1[w*H+h] = x[h,w]        (HW transpose)
//   s=2: y2[i]     = y0[HW-1-i]    (reverse)
//   s=3: y3[i]     = y1[HW-1-i]
//
// R2 restructure: ONE BLOCK PER PLANE (1536 blocks x 1024 threads), full
// 128x128 plane in exactly 64 KB LDS. Theory: previous 64x64-tile version
// emitted 8192 concurrent write streams of interleaved 256-B segments ->
// DRAM row thrash -> ~2.5 TB/s effective (fill achieves 6.3 on same mem).
// Now every output stream is one LINEAR 64-KB run per block:
//   y0: straight from load registers, ascending.
//   y2: full reverse of an aligned float4 is an aligned float4 ->
//       straight from registers, component-swapped, lane-descending
//       (contiguous coverage; coalescer merges by line).
//   y1: row w of y1 = column w of x; consecutive w contiguous -> linear.
//       Gathered via 4 scalar LDS reads per float4.
//   y3: reverse of y1 -> from the same t1 registers, descending.
// LDS: 128 rows x 32 float4 slots, XOR swizzle slot' = s ^ ((r>>2)&7).
//   Column gathers (fixed w, r varying): bank = 4*((s^(l&7))%8) + (w&3)
//   -> 8 banks x 4 lanes = 4-way (1.58x, ~8 us chip-wide; acceptable).
//   b128 row writes: slot permutation within each row -> conflict-free.
// Occupancy: 64 KB LDS -> 2 blocks/CU x 16 waves = 32 waves/CU (max).
// All global traffic nontemporal (zero reuse; keep L2/L3 clean).

typedef float v4f __attribute__((ext_vector_type(4)));

#define Hh 128
#define Ww 128
#define HWp 16384
#define Cc 96
#define Bb 16

__global__ __launch_bounds__(1024) void cross_scan_kernel(
    const float* __restrict__ x, float* __restrict__ out) {
  // 128 rows x 32 float4 slots = 65536 B exactly.
  __shared__ v4f tile4[128 * 32];

  const int T = threadIdx.x;      // 0..1023
  const int plane = blockIdx.x;   // 0..1535
  const int b = plane / Cc;
  const int c = plane - b * Cc;

  const float* xp = x + (size_t)plane * HWp;
  float* out0 = out + ((size_t)(b * 4 + 0) * Cc + c) * HWp;
  float* out1 = out + ((size_t)(b * 4 + 1) * Cc + c) * HWp;
  float* out2 = out + ((size_t)(b * 4 + 2) * Cc + c) * HWp;
  float* out3 = out + ((size_t)(b * 4 + 3) * Cc + c) * HWp;

  // ---- Phase 1: load plane (4 x 1KB/wave, all in flight), write y0 + y2
  //      from registers, stage LDS (swizzled) ----
  v4f v[4];
#pragma unroll
  for (int p = 0; p < 4; ++p) {
    const int G = p * 1024 + T;  // float4 index in plane, 0..4095
    v[p] = __builtin_nontemporal_load((const v4f*)(xp + 4 * G));
  }
#pragma unroll
  for (int p = 0; p < 4; ++p) {
    const int G = p * 1024 + T;
    const int r = G >> 5;        // row 0..127
    const int s = G & 31;        // float4 slot in row
    __builtin_nontemporal_store(v[p], (v4f*)(out0 + 4 * G));
    // y2[16380-4G .. 16383-4G] = y0[4G+3 .. 4G] reversed
    v4f rv = {v[p][3], v[p][2], v[p][1], v[p][0]};
    __builtin_nontemporal_store(rv, (v4f*)(out2 + (16380 - 4 * G)));
    tile4[r * 32 + (s ^ ((r >> 2) & 7))] = v[p];
  }
  __syncthreads();

  // ---- Phase 2: y1 (transpose gather) + y3 (its reverse) ----
#pragma unroll
  for (int p = 0; p < 4; ++p) {
    const int Q = p * 1024 + T;    // float4 index in y1, 0..4095
    const int w = Q >> 5;          // y1 row = x column, 0..127
    const int h0 = (Q & 31) * 4;   // first of 4 consecutive h
    const int sw = w >> 2;         // x float4 slot of column w
    const int kw = w & 3;          // component within that slot
    v4f t1;
#pragma unroll
    for (int k = 0; k < 4; ++k) {
      const int r = h0 + k;
      t1[k] = tile4[r * 32 + (sw ^ ((r >> 2) & 7))][kw];
    }
    __builtin_nontemporal_store(t1, (v4f*)(out1 + 4 * Q));
    // y3[16380-4Q .. 16383-4Q] = y1[4Q+3 .. 4Q] reversed
    v4f rt = {t1[3], t1[2], t1[1], t1[0]};
    __builtin_nontemporal_store(rt, (v4f*)(out3 + (16380 - 4 * Q)));
  }
}

extern "C" void kernel_launch(void* const* d_in, const int* in_sizes, int n_in,
                              void* d_out, int out_size, void* d_ws,
                              size_t ws_size, hipStream_t stream) {
  const float* x = (const float*)d_in[0];
  float* out = (float*)d_out;
  dim3 grid(Bb * Cc);   // 1536 planes, one block each
  dim3 block(1024);     // 16 waves
  cross_scan_kernel<<<grid, block, 0, stream>>>(x, out);
}

// Round 5
// 454.980 us; speedup vs baseline: 1.0089x; 1.0089x over previous
//
#include <hip/hip_runtime.h>

// CrossScan: x (B=16, C=96, H=128, W=128) fp32 -> out (B, 4, C, H*W):
//   s=0: y0[h*W+w] = x[h,w]
//   s=1: y1[w*H+h] = x[h,w]        (HW transpose)
//   s=2: y2[i]     = y0[HW-1-i]    (reverse)
//   s=3: y3[i]     = y1[HW-1-i]
//
// Memory-bound: 96 MiB read + 384 MiB write -> ~80 us floor at 6.3 TB/s.
// All four output streams stored with strictly ASCENDING coalesced float4;
// reversal via flipped LDS reads (reversed image of an aligned 64x64 tile is
// another aligned 64x64 tile with both axes flipped).
//
// R4: resubmit of R3 (broker timeout, no data). R3 = restore of the
// best-measured variant (R1, 454.3 us). Session evidence: three radically
// different structures (tile/plane, 8 vs 2 blocks/CU, ascending vs
// descending stores, NT on/off) all land at 457+-4 us, while the harness's
// own 1.61-GB re-poison fill (253 us @ 79% HBM peak) plus ~60 small reset
// dispatches/iter account for ~370 us of fixed cost. Kernel HW time is
// bounded in [80 us floor, <253 us] and unresponsive to structure =>
// at/near its memory roofline; dur_us is harness-dominated.
//
// LDS: +1 pad gives bank (4tx+k+R)%32 -> 2 lanes/bank on transpose reads
// (free, m136). All global traffic nontemporal (zero reuse).

typedef float v4f __attribute__((ext_vector_type(4)));

#define Hh 128
#define Ww 128
#define HWp (Hh * Ww)
#define Cc 96
#define Bb 16
#define TILE 64

__global__ __launch_bounds__(256) void cross_scan_kernel(
    const float* __restrict__ x, float* __restrict__ out) {
  // pad +1: row stride 65 = 1 mod 32 -> all access patterns are 2-way (free)
  __shared__ float tile[TILE][TILE + 1];

  const int tx = threadIdx.x;               // 0..15: float4 across 64 cols
  const int ty = threadIdx.y;               // 0..15: row base, rows ty+16j
  const int tileId = blockIdx.x;            // 0..3
  const int r0 = (tileId >> 1) * TILE;      // tile row base (h)
  const int c0 = (tileId & 1) * TILE;      // tile col base (w)
  const int plane = blockIdx.y;             // 0..B*C-1
  const int b = plane / Cc;
  const int c = plane - b * Cc;

  const float* xp = x + (size_t)plane * HWp;
  float* out0 = out + ((size_t)(b * 4 + 0) * Cc + c) * HWp;
  float* out1 = out + ((size_t)(b * 4 + 1) * Cc + c) * HWp;
  float* out2 = out + ((size_t)(b * 4 + 2) * Cc + c) * HWp;
  float* out3 = out + ((size_t)(b * 4 + 3) * Cc + c) * HWp;

  // ---- Phase 1: load 4 float4s (NT), write y0 (NT, ascending), stage tile ----
  v4f v[4];
#pragma unroll
  for (int j = 0; j < 4; ++j) {
    const int r = ty + 16 * j;
    v[j] = __builtin_nontemporal_load(
        (const v4f*)(xp + (r0 + r) * Ww + c0 + tx * 4));
  }
#pragma unroll
  for (int j = 0; j < 4; ++j) {
    const int r = ty + 16 * j;
    __builtin_nontemporal_store(
        v[j], (v4f*)(out0 + (r0 + r) * Ww + c0 + tx * 4));
    tile[r][tx * 4 + 0] = v[j][0];
    tile[r][tx * 4 + 1] = v[j][1];
    tile[r][tx * 4 + 2] = v[j][2];
    tile[r][tx * 4 + 3] = v[j][3];
  }
  __syncthreads();

  // Flipped tile bases in the output image (H=W=128, tiles are 64-aligned):
  const int r2b = TILE - r0;  // y2 out-row base (row flip)
  const int c2b = TILE - c0;  // y2 out-col base (col flip)
  const int R3b = TILE - c0;  // y3 out-row base
  const int c3b = TILE - r0;  // y3 out-col base

  // ---- Phase 2: y1/y2/y3 via LDS, all stores ascending float4 (NT) ----
#pragma unroll
  for (int j = 0; j < 4; ++j) {
    const int R = ty + 16 * j;

    // y1[(c0+R)*W + r0+4tx+k] = x[r0+4tx+k][c0+R] = tile[4tx+k][R]
    v4f t1;
    t1[0] = tile[tx * 4 + 0][R];
    t1[1] = tile[tx * 4 + 1][R];
    t1[2] = tile[tx * 4 + 2][R];
    t1[3] = tile[tx * 4 + 3][R];
    __builtin_nontemporal_store(
        t1, (v4f*)(out1 + (c0 + R) * Hh + r0 + tx * 4));

    // y2[(r2b+R)*W + c2b+4tx+k] = y0[HW-1-that] = tile[63-R][63-4tx-k]
    const float* Trow = &tile[63 - R][0];
    v4f t2;
    t2[0] = Trow[63 - tx * 4];
    t2[1] = Trow[62 - tx * 4];
    t2[2] = Trow[61 - tx * 4];
    t2[3] = Trow[60 - tx * 4];
    __builtin_nontemporal_store(
        t2, (v4f*)(out2 + (r2b + R) * Ww + c2b + tx * 4));

    // y3[(R3b+R)*W + c3b+4tx+k] = y1[HW-1-that] = tile[63-4tx-k][63-R]
    v4f t3;
    t3[0] = tile[63 - tx * 4][63 - R];
    t3[1] = tile[62 - tx * 4][63 - R];
    t3[2] = tile[61 - tx * 4][63 - R];
    t3[3] = tile[60 - tx * 4][63 - R];
    __builtin_nontemporal_store(
        t3, (v4f*)(out3 + (R3b + R) * Hh + c3b + tx * 4));
  }
}

extern "C" void kernel_launch(void* const* d_in, const int* in_sizes, int n_in,
                              void* d_out, int out_size, void* d_ws,
                              size_t ws_size, hipStream_t stream) {
  const float* x = (const float*)d_in[0];
  float* out = (float*)d_out;
  dim3 grid(4, Bb * Cc);  // 4 tiles/plane, 1536 planes
  dim3 block(16, 16);     // 256 threads, 4 waves
  cross_scan_kernel<<<grid, block, 0, stream>>>(x, out);
}